// Round 3
// baseline (828.697 us; speedup 1.0000x reference)
//
#include <hip/hip_runtime.h>
#include <hip/hip_bf16.h>

typedef _Float16 half4v __attribute__((ext_vector_type(4)));
typedef _Float16 half8v __attribute__((ext_vector_type(8)));
typedef float float4v __attribute__((ext_vector_type(4)));

#define L_SEQ 2048
#define EMB 1024
#define NH 16
#define DKV 64

__device__ inline void gll16(const void* g, void* l) {
  __builtin_amdgcn_global_load_lds((const __attribute__((address_space(1))) void*)g,
                                   (__attribute__((address_space(3))) void*)l, 16, 0, 0);
}

// ---------------------------------------------------------------------------
// Kernel A: cast X fp32 -> f16 (4096x1024), 8 elems/thread
// ---------------------------------------------------------------------------
__global__ __launch_bounds__(256) void xcast_kernel(const float* __restrict__ X,
                                                    _Float16* __restrict__ X16) {
  size_t i = ((size_t)blockIdx.x * 256 + threadIdx.x) * 8;
  float4v v0 = *(const float4v*)(X + i);
  float4v v1 = *(const float4v*)(X + i + 4);
  half8v h;
  h[0] = (_Float16)v0[0]; h[1] = (_Float16)v0[1]; h[2] = (_Float16)v0[2]; h[3] = (_Float16)v0[3];
  h[4] = (_Float16)v1[0]; h[5] = (_Float16)v1[1]; h[6] = (_Float16)v1[2]; h[7] = (_Float16)v1[3];
  *(half8v*)(X16 + i) = h;
}

// ---------------------------------------------------------------------------
// Kernel B: pack + transpose + cast W_qkv (fp32 [1024][3072]) -> Wt (f16 [2048][1024])
// ---------------------------------------------------------------------------
__global__ __launch_bounds__(256) void wpack_kernel(const float* __restrict__ W,
                                                    _Float16* __restrict__ Wt) {
  __shared__ float tile[32][33];
  int n0 = blockIdx.x * 32;
  int k0 = blockIdx.y * 32;
  int h = n0 >> 7;
  int wc = h * 192 + (n0 & 127);
  int tx = threadIdx.x & 31;
  int ty = threadIdx.x >> 5;
#pragma unroll
  for (int i = 0; i < 4; ++i) {
    int k = ty + i * 8;
    tile[k][tx] = W[(size_t)(k0 + k) * 3072 + wc + tx];
  }
  __syncthreads();
#pragma unroll
  for (int i = 0; i < 4; ++i) {
    int n = ty + i * 8;
    Wt[(size_t)(n0 + n) * 1024 + k0 + tx] = (_Float16)tile[tx][n];
  }
}

// ---------------------------------------------------------------------------
// Kernel C: Q/K projection GEMM (m97 structure). unchanged from round 2
// ---------------------------------------------------------------------------
__global__ __launch_bounds__(256) void qk_gemm_kernel(const _Float16* __restrict__ X16,
                                                      const _Float16* __restrict__ Wt,
                                                      const float* __restrict__ bias,
                                                      _Float16* __restrict__ Qh,
                                                      _Float16* __restrict__ Kh) {
  __shared__ _Float16 As[128 * 32];
  __shared__ _Float16 Bs[128 * 32];
  int n0 = blockIdx.x * 128;
  int m0 = blockIdx.y * 128;
  int t = threadIdx.x;
  int l = t & 63;
  int wv = t >> 6;
  int wm = wv >> 1, wn = wv & 1;
  int cl = l & 15, ko = (l >> 4) * 8;
  int srow = (l >> 2);
  int scol = (l & 3) * 8;
  float4v acc[4][4] = {};
  for (int k0 = 0; k0 < 1024; k0 += 32) {
#pragma unroll
    for (int c = 0; c < 2; ++c) {
      int rbase = wv * 32 + c * 16;
      gll16(X16 + (size_t)(m0 + rbase + srow) * 1024 + k0 + scol, &As[rbase * 32]);
      gll16(Wt + (size_t)(n0 + rbase + srow) * 1024 + k0 + scol, &Bs[rbase * 32]);
    }
    __syncthreads();
    half8v a[4], b[4];
#pragma unroll
    for (int mt = 0; mt < 4; ++mt) a[mt] = *(const half8v*)(&As[(wm * 64 + mt * 16 + cl) * 32 + ko]);
#pragma unroll
    for (int nt = 0; nt < 4; ++nt) b[nt] = *(const half8v*)(&Bs[(wn * 64 + nt * 16 + cl) * 32 + ko]);
#pragma unroll
    for (int mt = 0; mt < 4; ++mt)
#pragma unroll
      for (int nt = 0; nt < 4; ++nt)
        acc[mt][nt] = __builtin_amdgcn_mfma_f32_16x16x32_f16(a[mt], b[nt], acc[mt][nt], 0, 0, 0);
    __syncthreads();
  }
#pragma unroll
  for (int mt = 0; mt < 4; ++mt) {
#pragma unroll
    for (int nt = 0; nt < 4; ++nt) {
      int n_g = n0 + wn * 64 + nt * 16 + cl;
      int hh = n_g >> 7, rr = n_g & 127;
      float bv = bias[hh * 192 + rr];
      _Float16* dstbase = (rr < 64) ? Qh : Kh;
      int d = rr & 63;
#pragma unroll
      for (int r = 0; r < 4; ++r) {
        int row_g = m0 + wm * 64 + mt * 16 + (l >> 4) * 4 + r;
        int bb = row_g >> 11, lr = row_g & 2047;
        dstbase[(((size_t)bb * NH + hh) * L_SEQ + lr) * DKV + d] = (_Float16)(acc[mt][nt][r] + bv);
      }
    }
  }
}

// ---------------------------------------------------------------------------
// Kernel D: S = Q K^T / 8, softmax over j, write [B][H][L][L] fp32.
// DIAGNOSTIC: grid x3 (blocks >=1024 redo identical work -> benign same-value
// writes) so this dispatch exceeds the 2-GiB fills and surfaces in top-5 with
// its counters. Pass 2 now transposes P tiles through per-wave-private LDS
// (XOR-swizzled float4 granules, no barriers) and stores 512-B contiguous
// row spans (full cache lines) instead of 64-B segments.
// ---------------------------------------------------------------------------
__global__ __launch_bounds__(256) void attn_softmax_kernel(const _Float16* __restrict__ Qh,
                                                           const _Float16* __restrict__ Kh,
                                                           float* __restrict__ out) {
  __shared__ float Plds[4 * 16 * 128];  // 32 KB, per-wave-private 8 KB regions
  int base = blockIdx.x & 1023;  // replicas: blockIdx.x>>10 in {0,1,2}
  int xcd = base & 7;
  int rest = base >> 3;
  int rb = rest & 31;
  int bh = ((rest >> 5) << 3) + xcd;  // bijective XCD swizzle
  int t = threadIdx.x;
  int l = t & 63;
  int wv = t >> 6;
  int cl = l & 15;          // q-col in MFMA frag
  int hi = l >> 4;          // 0..3
  int ko = hi * 8;
  int qbase = rb * 64 + wv * 16;
  const _Float16* Qb = Qh + ((size_t)bh * L_SEQ + qbase) * DKV;
  const _Float16* Kb = Kh + (size_t)bh * L_SEQ * DKV;
  half8v aq0 = *(const half8v*)(Qb + cl * DKV + ko);
  half8v aq1 = *(const half8v*)(Qb + cl * DKV + 32 + ko);
  const float SC = 0.18033688011112042f;  // log2(e)/sqrt(64)

  // ---- Pass 1: row sums (no stores) ----
  float lsum = 0.f;
#pragma unroll 4
  for (int j0 = 0; j0 < L_SEQ; j0 += 16) {
    const _Float16* Kp = Kb + (size_t)(j0 + cl) * DKV;
    half8v b0 = *(const half8v*)(Kp + ko);
    half8v b1 = *(const half8v*)(Kp + 32 + ko);
    float4v acc = {};
    acc = __builtin_amdgcn_mfma_f32_16x16x32_f16(b0, aq0, acc, 0, 0, 0);
    acc = __builtin_amdgcn_mfma_f32_16x16x32_f16(b1, aq1, acc, 0, 0, 0);
    lsum += __builtin_amdgcn_exp2f(acc[0] * SC) + __builtin_amdgcn_exp2f(acc[1] * SC) +
            __builtin_amdgcn_exp2f(acc[2] * SC) + __builtin_amdgcn_exp2f(acc[3] * SC);
  }
  lsum += __shfl_xor(lsum, 16);
  lsum += __shfl_xor(lsum, 32);
  float inv = 1.0f / lsum;

  // ---- Pass 2: recompute, normalize, LDS-transpose, full-line stores ----
  float* Pw = Plds + wv * (16 * 128);
  int sr = l >> 5;        // row-in-pair for store phase
  int sc = l & 31;        // col granule for store phase
  size_t orow = (size_t)bh * L_SEQ + qbase;
  for (int j0 = 0; j0 < L_SEQ; j0 += 128) {
    float4v p[8];
#pragma unroll
    for (int jt = 0; jt < 8; ++jt) {
      const _Float16* Kp = Kb + (size_t)(j0 + jt * 16 + cl) * DKV;
      half8v b0 = *(const half8v*)(Kp + ko);
      half8v b1 = *(const half8v*)(Kp + 32 + ko);
      float4v acc = {};
      acc = __builtin_amdgcn_mfma_f32_16x16x32_f16(b0, aq0, acc, 0, 0, 0);
      acc = __builtin_amdgcn_mfma_f32_16x16x32_f16(b1, aq1, acc, 0, 0, 0);
      float4v pv;
      pv[0] = __builtin_amdgcn_exp2f(acc[0] * SC) * inv;
      pv[1] = __builtin_amdgcn_exp2f(acc[1] * SC) * inv;
      pv[2] = __builtin_amdgcn_exp2f(acc[2] * SC) * inv;
      pv[3] = __builtin_amdgcn_exp2f(acc[3] * SC) * inv;
      p[jt] = pv;
    }
    // LDS write: lane holds q=cl, j-granule c=jt*4+hi; slot = c ^ q (XOR swizzle)
#pragma unroll
    for (int jt = 0; jt < 8; ++jt) {
      int cslot = (jt * 4 + hi) ^ cl;
      *(float4v*)(&Pw[cl * 128 + 4 * cslot]) = p[jt];
    }
    // LDS read + global store: per op 2 rows x 512 B contiguous spans
#pragma unroll
    for (int i = 0; i < 8; ++i) {
      int row = i * 2 + sr;
      int slot = sc ^ row;
      float4v v = *(const float4v*)(&Pw[row * 128 + 4 * slot]);
      *(float4v*)(out + (orow + row) * L_SEQ + j0 + 4 * sc) = v;
    }
  }
}

// ---------------------------------------------------------------------------
extern "C" void kernel_launch(void* const* d_in, const int* in_sizes, int n_in,
                              void* d_out, int out_size, void* d_ws, size_t ws_size,
                              hipStream_t stream) {
  const float* X = (const float*)d_in[0];
  const float* W = (const float*)d_in[1];
  const float* bias = (const float*)d_in[2];
  float* out = (float*)d_out;
  char* ws = (char*)d_ws;
  _Float16* Wt = (_Float16*)ws;                       // 4 MB
  _Float16* Qh = (_Float16*)(ws + (4ull << 20));      // 8 MB
  _Float16* Kh = (_Float16*)(ws + (12ull << 20));     // 8 MB
  _Float16* X16 = (_Float16*)(ws + (20ull << 20));    // 8 MB (total 28 MB)

  xcast_kernel<<<2048, 256, 0, stream>>>(X, X16);
  wpack_kernel<<<dim3(64, 32), 256, 0, stream>>>(W, Wt);
  qk_gemm_kernel<<<dim3(16, 32), 256, 0, stream>>>(X16, Wt, bias, Qh, Kh);
  // DIAGNOSTIC x3 grid: surfaces attn in rocprof top-5 above the 2-GiB fills.
  attn_softmax_kernel<<<3072, 256, 0, stream>>>(Qh, Kh, out);
}

// Round 4
// 193.903 us; speedup vs baseline: 4.2738x; 4.2738x over previous
//
#include <hip/hip_runtime.h>
#include <hip/hip_bf16.h>

typedef _Float16 half4v __attribute__((ext_vector_type(4)));
typedef _Float16 half8v __attribute__((ext_vector_type(8)));
typedef float float4v __attribute__((ext_vector_type(4)));

#define L_SEQ 2048
#define EMB 1024
#define NH 16
#define DKV 64

__device__ inline void gll16(const void* g, void* l) {
  __builtin_amdgcn_global_load_lds((const __attribute__((address_space(1))) void*)g,
                                   (__attribute__((address_space(3))) void*)l, 16, 0, 0);
}

// ---------------------------------------------------------------------------
// Kernel A: cast X fp32 -> f16 (4096x1024), 8 elems/thread
// ---------------------------------------------------------------------------
__global__ __launch_bounds__(256) void xcast_kernel(const float* __restrict__ X,
                                                    _Float16* __restrict__ X16) {
  size_t i = ((size_t)blockIdx.x * 256 + threadIdx.x) * 8;
  float4v v0 = *(const float4v*)(X + i);
  float4v v1 = *(const float4v*)(X + i + 4);
  half8v h;
  h[0] = (_Float16)v0[0]; h[1] = (_Float16)v0[1]; h[2] = (_Float16)v0[2]; h[3] = (_Float16)v0[3];
  h[4] = (_Float16)v1[0]; h[5] = (_Float16)v1[1]; h[6] = (_Float16)v1[2]; h[7] = (_Float16)v1[3];
  *(half8v*)(X16 + i) = h;
}

// ---------------------------------------------------------------------------
// Kernel B: pack + transpose + cast W_qkv (fp32 [1024][3072]) -> Wt (f16 [2048][1024])
// ---------------------------------------------------------------------------
__global__ __launch_bounds__(256) void wpack_kernel(const float* __restrict__ W,
                                                    _Float16* __restrict__ Wt) {
  __shared__ float tile[32][33];
  int n0 = blockIdx.x * 32;
  int k0 = blockIdx.y * 32;
  int h = n0 >> 7;
  int wc = h * 192 + (n0 & 127);
  int tx = threadIdx.x & 31;
  int ty = threadIdx.x >> 5;
#pragma unroll
  for (int i = 0; i < 4; ++i) {
    int k = ty + i * 8;
    tile[k][tx] = W[(size_t)(k0 + k) * 3072 + wc + tx];
  }
  __syncthreads();
#pragma unroll
  for (int i = 0; i < 4; ++i) {
    int n = ty + i * 8;
    Wt[(size_t)(n0 + n) * 1024 + k0 + tx] = (_Float16)tile[tx][n];
  }
}

// ---------------------------------------------------------------------------
// Kernel C: Q/K projection GEMM (m97 structure). unchanged
// ---------------------------------------------------------------------------
__global__ __launch_bounds__(256) void qk_gemm_kernel(const _Float16* __restrict__ X16,
                                                      const _Float16* __restrict__ Wt,
                                                      const float* __restrict__ bias,
                                                      _Float16* __restrict__ Qh,
                                                      _Float16* __restrict__ Kh) {
  __shared__ _Float16 As[128 * 32];
  __shared__ _Float16 Bs[128 * 32];
  int n0 = blockIdx.x * 128;
  int m0 = blockIdx.y * 128;
  int t = threadIdx.x;
  int l = t & 63;
  int wv = t >> 6;
  int wm = wv >> 1, wn = wv & 1;
  int cl = l & 15, ko = (l >> 4) * 8;
  int srow = (l >> 2);
  int scol = (l & 3) * 8;
  float4v acc[4][4] = {};
  for (int k0 = 0; k0 < 1024; k0 += 32) {
#pragma unroll
    for (int c = 0; c < 2; ++c) {
      int rbase = wv * 32 + c * 16;
      gll16(X16 + (size_t)(m0 + rbase + srow) * 1024 + k0 + scol, &As[rbase * 32]);
      gll16(Wt + (size_t)(n0 + rbase + srow) * 1024 + k0 + scol, &Bs[rbase * 32]);
    }
    __syncthreads();
    half8v a[4], b[4];
#pragma unroll
    for (int mt = 0; mt < 4; ++mt) a[mt] = *(const half8v*)(&As[(wm * 64 + mt * 16 + cl) * 32 + ko]);
#pragma unroll
    for (int nt = 0; nt < 4; ++nt) b[nt] = *(const half8v*)(&Bs[(wn * 64 + nt * 16 + cl) * 32 + ko]);
#pragma unroll
    for (int mt = 0; mt < 4; ++mt)
#pragma unroll
      for (int nt = 0; nt < 4; ++nt)
        acc[mt][nt] = __builtin_amdgcn_mfma_f32_16x16x32_f16(a[mt], b[nt], acc[mt][nt], 0, 0, 0);
    __syncthreads();
  }
#pragma unroll
  for (int mt = 0; mt < 4; ++mt) {
#pragma unroll
    for (int nt = 0; nt < 4; ++nt) {
      int n_g = n0 + wn * 64 + nt * 16 + cl;
      int hh = n_g >> 7, rr = n_g & 127;
      float bv = bias[hh * 192 + rr];
      _Float16* dstbase = (rr < 64) ? Qh : Kh;
      int d = rr & 63;
#pragma unroll
      for (int r = 0; r < 4; ++r) {
        int row_g = m0 + wm * 64 + mt * 16 + (l >> 4) * 4 + r;
        int bb = row_g >> 11, lr = row_g & 2047;
        dstbase[(((size_t)bb * NH + hh) * L_SEQ + lr) * DKV + d] = (_Float16)(acc[mt][nt][r] + bv);
      }
    }
  }
}

// ---------------------------------------------------------------------------
// Kernel D: S = Q K^T / 8, softmax over j, write [B][H][L][L] fp32.
// LDS-staged K (64x64 f16 tiles, global_load_lds, double-buffered, source-
// swizzled granules so ds_read_b128 fragments are conflict-free). Two passes
// (sum, then recompute+normalize+store). Stores go through a per-wave-private
// XOR-swizzled LDS transpose -> 256B contiguous spans.
// ---------------------------------------------------------------------------
__global__ __launch_bounds__(256) void attn_softmax_kernel(const _Float16* __restrict__ Qh,
                                                           const _Float16* __restrict__ Kh,
                                                           float* __restrict__ out) {
  __shared__ _Float16 Ks[2][64 * 64];  // 16 KB (dbuf), row stride 64 f16, granule-swizzled
  __shared__ float Ps[4][16 * 64];     // 16 KB, per-wave P transpose chunks
  int id = blockIdx.x;
  int xcd = id & 7;
  int rest = id >> 3;
  int rb = rest & 31;
  int bh = ((rest >> 5) << 3) + xcd;  // bijective XCD swizzle: same-bh -> same XCD
  int t = threadIdx.x;
  int l = t & 63;
  int wv = t >> 6;
  int cl = l & 15;   // MFMA col (q within wave's 16 rows)
  int hi = l >> 4;   // MFMA k-chunk / j-subrow group
  int qbase = rb * 64 + wv * 16;
  const _Float16* Qb = Qh + ((size_t)bh * L_SEQ + qbase) * DKV;
  const _Float16* Kb = Kh + (size_t)bh * L_SEQ * DKV;
  half8v aq0 = *(const half8v*)(Qb + cl * DKV + hi * 8);
  half8v aq1 = *(const half8v*)(Qb + cl * DKV + 32 + hi * 8);
  const float SC = 0.18033688011112042f;  // log2(e)/sqrt(64)

  // Stage one 64x64 f16 K tile: linear LDS dest (base + lane*16), per-lane
  // global src pre-swizzled: granule gi -> row r=gi>>3, slot s=gi&7 holds
  // K[j0+r][8*(s^(r&7)) ..]. Read side applies the same XOR.
#define STAGE(bufi, j0)                                                     \
  {                                                                         \
    _Pragma("unroll") for (int c = 0; c < 2; ++c) {                         \
      int gi = (wv * 2 + c) * 64 + l;                                       \
      int r_ = gi >> 3, s_ = gi & 7;                                        \
      gll16(Kb + (size_t)((j0) + r_) * DKV + 8 * (s_ ^ (r_ & 7)),           \
            &Ks[bufi][(wv * 2 + c) * 512]);                                 \
    }                                                                       \
  }

  // ---- Pass 1: row sums ----
  float lsum = 0.f;
  int buf = 0;
  STAGE(0, 0);
  __syncthreads();
  for (int jt = 0; jt < 32; ++jt) {
    if (jt + 1 < 32) STAGE(buf ^ 1, (jt + 1) * 64);
#pragma unroll
    for (int s4 = 0; s4 < 4; ++s4) {
      int row = s4 * 16 + cl;
      half8v b0 = *(const half8v*)(&Ks[buf][row * 64 + 8 * (hi ^ (cl & 7))]);
      half8v b1 = *(const half8v*)(&Ks[buf][row * 64 + 8 * ((hi + 4) ^ (cl & 7))]);
      float4v acc = {};
      acc = __builtin_amdgcn_mfma_f32_16x16x32_f16(b0, aq0, acc, 0, 0, 0);
      acc = __builtin_amdgcn_mfma_f32_16x16x32_f16(b1, aq1, acc, 0, 0, 0);
      lsum += __builtin_amdgcn_exp2f(acc[0] * SC) + __builtin_amdgcn_exp2f(acc[1] * SC) +
              __builtin_amdgcn_exp2f(acc[2] * SC) + __builtin_amdgcn_exp2f(acc[3] * SC);
    }
    __syncthreads();
    buf ^= 1;
  }
  lsum += __shfl_xor(lsum, 16);
  lsum += __shfl_xor(lsum, 32);
  float inv = 1.0f / lsum;

  // ---- Pass 2: recompute, normalize, LDS transpose, contiguous stores ----
  float* Pw = Ps[wv];
  size_t orow = (size_t)bh * L_SEQ + qbase;
  buf = 0;
  STAGE(0, 0);
  __syncthreads();
  for (int jt = 0; jt < 32; ++jt) {
    if (jt + 1 < 32) STAGE(buf ^ 1, (jt + 1) * 64);
#pragma unroll
    for (int s4 = 0; s4 < 4; ++s4) {
      int row = s4 * 16 + cl;
      half8v b0 = *(const half8v*)(&Ks[buf][row * 64 + 8 * (hi ^ (cl & 7))]);
      half8v b1 = *(const half8v*)(&Ks[buf][row * 64 + 8 * ((hi + 4) ^ (cl & 7))]);
      float4v acc = {};
      acc = __builtin_amdgcn_mfma_f32_16x16x32_f16(b0, aq0, acc, 0, 0, 0);
      acc = __builtin_amdgcn_mfma_f32_16x16x32_f16(b1, aq1, acc, 0, 0, 0);
      float4v pv;
      pv[0] = __builtin_amdgcn_exp2f(acc[0] * SC) * inv;
      pv[1] = __builtin_amdgcn_exp2f(acc[1] * SC) * inv;
      pv[2] = __builtin_amdgcn_exp2f(acc[2] * SC) * inv;
      pv[3] = __builtin_amdgcn_exp2f(acc[3] * SC) * inv;
      int jj = s4 * 4 + hi;  // float4-granule within the 64-j chunk
      *(float4v*)(&Pw[cl * 64 + 4 * (jj ^ cl)]) = pv;
    }
    // read back transposed; 4 rows x 256B contiguous per instr
#pragma unroll
    for (int i = 0; i < 4; ++i) {
      int row = i * 4 + hi;
      int g = cl;
      float4v v = *(const float4v*)(&Pw[row * 64 + 4 * (g ^ row)]);
      *(float4v*)(out + (orow + row) * L_SEQ + jt * 64 + 4 * g) = v;
    }
    __syncthreads();
    buf ^= 1;
  }
#undef STAGE
}

// ---------------------------------------------------------------------------
extern "C" void kernel_launch(void* const* d_in, const int* in_sizes, int n_in,
                              void* d_out, int out_size, void* d_ws, size_t ws_size,
                              hipStream_t stream) {
  const float* X = (const float*)d_in[0];
  const float* W = (const float*)d_in[1];
  const float* bias = (const float*)d_in[2];
  float* out = (float*)d_out;
  char* ws = (char*)d_ws;
  _Float16* Wt = (_Float16*)ws;                       // 4 MB
  _Float16* Qh = (_Float16*)(ws + (4ull << 20));      // 8 MB
  _Float16* Kh = (_Float16*)(ws + (12ull << 20));     // 8 MB
  _Float16* X16 = (_Float16*)(ws + (20ull << 20));    // 8 MB (total 28 MB)

  xcast_kernel<<<2048, 256, 0, stream>>>(X, X16);
  wpack_kernel<<<dim3(64, 32), 256, 0, stream>>>(W, Wt);
  qk_gemm_kernel<<<dim3(16, 32), 256, 0, stream>>>(X16, Wt, bias, Qh, Kh);
  attn_softmax_kernel<<<1024, 256, 0, stream>>>(Qh, Kh, out);
}